// Round 13
// baseline (264.627 us; speedup 1.0000x reference)
//
#include <hip/hip_runtime.h>

typedef _Float16 f16;
typedef _Float16 f16x4 __attribute__((ext_vector_type(4)));
typedef _Float16 f16x8 __attribute__((ext_vector_type(8)));
typedef float f32x4 __attribute__((ext_vector_type(4)));
typedef unsigned short u16;
typedef unsigned int u32;

#define NATOMS 65536
#define CAP 17920            // per-species atom capacity (~+13 sigma vs expected 16384)

// ---------------- workspace layout (lists + packed weights only) ---------------
#define WS_LISTS_OFF 256
#define WS_W_OFF 524544
#define WS_W_ELEMS 350208
#define WS_NEEDED (WS_W_OFF + WS_W_ELEMS * 2)

#define BLKF 64   // fused: blocks per species -> grid 256 (640 thr, 1 block/CU)

// aev staging geometry: 16-atom tile
#define ROWB 1536            // bytes per aev row (384 f32)
#define ROWH 768             // bytes per LDS row (384 f16)
#define TILEH 12288          // 16 x 768 B f16 tile

struct ConvJob { const float* src; int K, N, KS, NT, CK, off; };

struct PrepParams {
  const int* species;
  int* counts;
  u16* lists;
  f16* wbase;
  ConvJob jobs[16];
};

struct GemmParams {
  const float* aev;
  const float* b0;
  const float* b1;
  const float* bias[4][4];
  const float* w3src[4];    // original fp32 layer-3 weights [96][1]
  const f16* w[4][4];       // fragment-packed, chunk-major (frag = ks*NT + nt)
  const int* counts;
  const u16* lists;
  float* out;
  int Nreal0[4];            // {160,144,128,128}
  int Nreal1[4];            // {128,112,112,112}
};

// A-fragment bundle passed BY VALUE so SROA keeps it in VGPRs.
template <int N> struct AF { f16x8 v[N]; };

// ---------------- prep: routing (blocks 0..255) + weight pack (blocks 256..735) ----
__global__ __launch_bounds__(256) void prep_kernel(PrepParams p) {
  int tid = threadIdx.x;
  if (blockIdx.x < 256) {
    __shared__ int wcnt[4][4];
    __shared__ int wbase[4][4];
    int i = blockIdx.x * 256 + tid;
    int s = p.species[i];
    int wave = tid >> 6, lane = tid & 63;
    unsigned long long m[4];
    #pragma unroll
    for (int t = 0; t < 4; t++) {
      m[t] = __ballot(s == t);
      if (lane == 0) wcnt[wave][t] = __popcll(m[t]);
    }
    __syncthreads();
    if (tid < 4) {
      int t = tid;
      int c0 = wcnt[0][t], c1 = wcnt[1][t], c2 = wcnt[2][t], c3 = wcnt[3][t];
      int base = atomicAdd(&p.counts[t], c0 + c1 + c2 + c3);
      wbase[0][t] = base;
      wbase[1][t] = base + c0;
      wbase[2][t] = base + c0 + c1;
      wbase[3][t] = base + c0 + c1 + c2;
    }
    __syncthreads();
    int rnk = __popcll(m[s] & ((1ull << lane) - 1ull));
    p.lists[s * NATOMS + wbase[wave][s] + rnk] = (u16)i;
  } else {
    // pack fp32 [K][N] -> fp16 fragments, chunk-major consumption order
    int bx = blockIdx.x - 256;
    int job = bx / 30, bxin = bx - job * 30;
    ConvJob jb = p.jobs[job];
    int e = bxin * 256 + tid;
    int nslots = jb.KS * jb.NT * 64;
    if (e >= nslots) return;
    int frag = e >> 6, lane = e & 63;
    int c = frag / (jb.CK * jb.NT);
    int rem = frag - c * (jb.CK * jb.NT);
    int ckc = min(jb.CK, jb.KS - c * jb.CK);
    int nt = rem / ckc, ki = rem - nt * ckc;
    int ks = c * jb.CK + ki;
    int q = lane >> 4, nlo = lane & 15;
    int n = nt * 16 + nlo;
    int k0 = ks * 32 + q * 8;
    f16x8 v;
    #pragma unroll
    for (int j = 0; j < 8; j++) {
      int k = k0 + j;
      float x = (n < jb.N && k < jb.K) ? jb.src[k * jb.N + n] : 0.f;
      v[j] = (f16)x;
    }
    *(f16x8*)(p.wbase + jb.off + (size_t)e * 8) = v;
  }
}

__device__ __forceinline__ float celu01(float v) {
  return v > 0.f ? v : 0.1f * (__expf(v * 10.f) - 1.f);
}

// stage one 1KB fragment (64 lanes x 16B) global -> LDS (weight staging)
__device__ __forceinline__ void stage_frag(const f16* g, f16* l, int lane) {
  __builtin_amdgcn_global_load_lds(
      (const __attribute__((address_space(1))) u32*)(g + lane * 8),
      (__attribute__((address_space(3))) u32*)l, 16, 0, 0);
}

// ============================================================================
// fused : aev(f32)[gathered] -> L0 -> celu -> (z0 in LDS) -> L1 -> celu
//         -> (in-place transpose) -> L2 -> celu -> dot w3 -> shifter -> out.
//
// R13 = R10 EXACTLY (verified 63.5us, VGPR 84) + ONE variable: register
// prefetch depth 2 -> 3.  Three static load sets (ldA/ldB/ldC, rule #20:
// batch fully unrolled so all set indexing is compile-time).  Load->ds_write
// distance grows 1 -> 2 barrier periods; per-period cadence, LDS layout,
// W1/W2 residency, phase B all byte-identical to R10.  Tests the surviving
// hypothesis: each period stalls at write_lds' vmcnt because one period of
// work (<1000cy) doesn't cover the gather's effective latency (R12 killed
// the barrier-cadence theory: 2x work/period = +19% time).
// ============================================================================
template <int NT0, int KS1>   // H/C: <10,5>  N/O: <8,4>
__device__ void fused_body(const GemmParams& p, int s, int bl, char* smem) {
  constexpr int LDSA_OFF = 2 * TILEH;                  // 24576
  constexpr int TSTRIDE = 16 * 168;                    // f16 per ldsA tile
  constexpr int W1_OFF = LDSA_OFF + 8 * TSTRIDE * 2;   // 67584
  constexpr int W2_OFF = W1_OFF + 40 * 512 * 2;        // 108544
  constexpr int ATOMS_OFF = W2_OFF + 24 * 512 * 2;     // 133120
  constexpr int NF1 = KS1 * 8;

  int tid = threadIdx.x, w = tid >> 6, lane = tid & 63;
  int q = lane >> 4, nlo = lane & 15;
  int cnt = min(p.counts[s], CAP);
  int ntiles = (cnt + 15) >> 4;
  int tpb = (ntiles + BLKF - 1) / BLKF;
  int t0 = bl * tpb;
  int nt_blk = min(ntiles - t0, tpb);
  if (nt_blk <= 0) return;               // uniform block-wide exit (before barriers)

  f16* ldsA = (f16*)(smem + LDSA_OFF);
  f16* W1 = (f16*)(smem + W1_OFF);
  f16* W2 = (f16*)(smem + W2_OFF);
  u16* atoms_l = (u16*)(smem + ATOMS_OFF);

  // W1/W2 -> LDS once per block (wave-uniform loop)
  const f16* g1 = p.w[s][1];
  const f16* g2 = p.w[s][2];
  for (int f = w; f < NF1 + 24; f += 10) {
    if (f < NF1) stage_frag(g1 + (size_t)f * 512, W1 + f * 512, lane);
    else stage_frag(g2 + (size_t)(f - NF1) * 512, W2 + (f - NF1) * 512, lane);
  }

  // W0 fragments (A-operand: row=n) + phase-A bias, VGPR-resident
  f16x8 wf[12];
  float bvv[4];
  if (w < NT0) {
    const f16* wg = p.w[s][0];
    #pragma unroll
    for (int ks = 0; ks < 12; ks++)
      wf[ks] = *(const f16x8*)(wg + (size_t)(ks * NT0 + w) * 512 + lane * 8);
    #pragma unroll
    for (int r = 0; r < 4; r++) {
      int n = w * 16 + q * 4 + r;
      bvv[r] = (n < p.Nreal0[s]) ? p.bias[s][0][n] : 0.f;
    }
  }

  // phase-B constants (persist across batches)
  int Nr1 = p.Nreal1[s];
  const float* bias1 = p.bias[s][1];
  const float* bias2 = p.bias[s][2];
  const float* w3 = p.w3src[s];
  float bv1[8], b2v[6], w3v[6];
  #pragma unroll
  for (int nt = 0; nt < 8; nt++) {
    int n = nt * 16 + nlo;
    bv1[nt] = (n < Nr1) ? bias1[n] : 0.f;
  }
  #pragma unroll
  for (int nt = 0; nt < 6; nt++) {
    int n = nt * 16 + nlo;    // 0..95, all real
    b2v[nt] = bias2[n];
    w3v[nt] = w3[n];
  }
  float b3 = p.bias[s][3][0];
  float b0v = p.b0[s], b1v = p.b1[s];

  // atom ids -> LDS (subsequent reads are lgkm ops; tpb<=18 -> <=288 entries)
  const u16* list = p.lists + s * NATOMS;
  for (int idx = tid; idx < nt_blk * 16; idx += 640)
    atoms_l[idx] = list[min(t0 * 16 + idx, cnt - 1)];
  __syncthreads();   // drains W1/W2 DMAs + wf/bias/atom loads; pipeline empty

  bool stager = (w < 8);
  int frow[3], fintra[3];
  #pragma unroll
  for (int j = 0; j < 3; j++) {
    int o32 = (w + 8 * j) * 1024 + lane * 16;
    frow[j] = o32 / ROWB;
    fintra[j] = o32 - frow[j] * ROWB;
  }

  // three static in-flight load sets (tile t uses set (t-lo)%3)
  f32x4 ldA[3], ldB[3], ldC[3];
  auto issueA = [&](int i) {
    #pragma unroll
    for (int j = 0; j < 3; j++) {
      int atom = atoms_l[i * 16 + frow[j]];
      ldA[j] = *(const f32x4*)((const char*)p.aev + (size_t)atom * ROWB + fintra[j]);
    }
  };
  auto issueB = [&](int i) {
    #pragma unroll
    for (int j = 0; j < 3; j++) {
      int atom = atoms_l[i * 16 + frow[j]];
      ldB[j] = *(const f32x4*)((const char*)p.aev + (size_t)atom * ROWB + fintra[j]);
    }
  };
  auto issueC = [&](int i) {
    #pragma unroll
    for (int j = 0; j < 3; j++) {
      int atom = atoms_l[i * 16 + frow[j]];
      ldC[j] = *(const f32x4*)((const char*)p.aev + (size_t)atom * ROWB + fintra[j]);
    }
  };
  auto writeA = [&](int i) {             // ldA -> f16 -> ring slot i&1, swizzled
    char* buf = smem + (i & 1) * TILEH;
    #pragma unroll
    for (int j = 0; j < 3; j++) {
      int o16 = (w + 8 * j) * 512 + lane * 8;
      int addr = o16 ^ ((frow[j] & 7) << 4);
      f16x4 h = {(f16)ldA[j][0], (f16)ldA[j][1], (f16)ldA[j][2], (f16)ldA[j][3]};
      *(f16x4*)(buf + addr) = h;
    }
  };
  auto writeB = [&](int i) {
    char* buf = smem + (i & 1) * TILEH;
    #pragma unroll
    for (int j = 0; j < 3; j++) {
      int o16 = (w + 8 * j) * 512 + lane * 8;
      int addr = o16 ^ ((frow[j] & 7) << 4);
      f16x4 h = {(f16)ldB[j][0], (f16)ldB[j][1], (f16)ldB[j][2], (f16)ldB[j][3]};
      *(f16x4*)(buf + addr) = h;
    }
  };
  auto writeC = [&](int i) {
    char* buf = smem + (i & 1) * TILEH;
    #pragma unroll
    for (int j = 0; j < 3; j++) {
      int o16 = (w + 8 * j) * 512 + lane * 8;
      int addr = o16 ^ ((frow[j] & 7) << 4);
      f16x4 h = {(f16)ldC[j][0], (f16)ldC[j][1], (f16)ldC[j][2], (f16)ldC[j][3]};
      *(f16x4*)(buf + addr) = h;
    }
  };
  auto computeT = [&](int i, int lo) {   // L0 MFMA on ring slot i&1 -> ldsA[i-lo]
    const char* buf = smem + (i & 1) * TILEH;
    int swz = (nlo & 7) << 4;
    int base = nlo * ROWH + q * 16;
    f32x4 acc = {0.f, 0.f, 0.f, 0.f};
    #pragma unroll
    for (int ks = 0; ks < 12; ks++) {
      f16x8 a = *(const f16x8*)(buf + ((base + ks * 64) ^ swz));
      acc = __builtin_amdgcn_mfma_f32_16x16x32_f16(wf[ks], a, acc, 0, 0, 0);
    }
    f16* A = ldsA + (i - lo) * TSTRIDE;
    f16x4 o;
    #pragma unroll
    for (int r = 0; r < 4; r++) o[r] = (f16)celu01(acc[r] + bvv[r]);
    *(f16x4*)(A + nlo * 168 + w * 16 + q * 4) = o;
  };

  for (int lo = 0; lo < nt_blk; lo += 8) {
    int hi = min(nt_blk, lo + 8);
    int n = hi - lo;                     // 1..8, block-uniform

    // ---- phase A prologue: 3 tiles issued, tile lo written ----
    if (stager) {
      issueA(lo);
      if (n > 1) issueB(lo + 1);
      if (n > 2) issueC(lo + 2);
      writeA(lo);                        // waits exactly on ldA (B,C in flight)
    }
    asm volatile("s_waitcnt lgkmcnt(0)" ::: "memory");
    __builtin_amdgcn_s_barrier();

    // ---- phase A: 8 unrolled bodies; set rotation tile%3; issue 3 ahead ----
    // body ii: issue(ii+3) into set ii%3 (freed: tile ii written body ii-1);
    //          write(ii+1) from set (ii+1)%3 (loaded 2 periods ago);
    //          compute tile ii from ring slot ii&1.
    #define BODY(ii, WSET, ISET)                                    \
    if (ii < n) {                                                   \
      if (stager) {                                                 \
        if (ii + 3 < n) ISET(lo + ii + 3);                          \
        if (ii + 1 < n) WSET(lo + ii + 1);                          \
      }                                                             \
      if (w < NT0) computeT(lo + ii, lo);                           \
      asm volatile("s_waitcnt lgkmcnt(0)" ::: "memory");            \
      __builtin_amdgcn_s_barrier();                                 \
    }
    BODY(0, writeB, issueA)
    BODY(1, writeC, issueB)
    BODY(2, writeA, issueC)
    BODY(3, writeB, issueA)
    BODY(4, writeC, issueB)
    BODY(5, writeA, issueC)
    BODY(6, writeB, issueA)
    BODY(7, writeC, issueB)
    #undef BODY

    // ---- phase B: wave w consumes ldsA[w] (tile lo+w); W1/W2 from LDS ----
    if (w < 8 && lo + w < hi) {
      int i = lo + w;
      f16* A = ldsA + w * TSTRIDE;
      AF<KS1> a1;
      #pragma unroll
      for (int ks = 0; ks < KS1; ks++)
        a1.v[ks] = *(const f16x8*)(A + nlo * 168 + ks * 32 + q * 8);
      f32x4 acc1[8];
      #pragma unroll
      for (int nt = 0; nt < 8; nt++) acc1[nt] = f32x4{0.f, 0.f, 0.f, 0.f};
      #pragma unroll
      for (int ks = 0; ks < KS1; ks++) {
        #pragma unroll
        for (int nt = 0; nt < 8; nt++) {
          f16x8 b = *(const f16x8*)(W1 + (ks * 8 + nt) * 512 + lane * 8);
          acc1[nt] = __builtin_amdgcn_mfma_f32_16x16x32_f16(a1.v[ks], b, acc1[nt], 0, 0, 0);
        }
      }
      // z1-celu transpose into the SAME tile region (a1 already in regs;
      // every write depends on all a1 reads through acc1 -> no hazard)
      #pragma unroll
      for (int nt = 0; nt < 8; nt++) {
        #pragma unroll
        for (int r = 0; r < 4; r++)
          A[(q * 4 + r) * 168 + nt * 16 + nlo] = (f16)celu01(acc1[nt][r] + bv1[nt]);
      }
      AF<4> a2;
      #pragma unroll
      for (int ks = 0; ks < 4; ks++)
        a2.v[ks] = *(const f16x8*)(A + nlo * 168 + ks * 32 + q * 8);
      f32x4 acc2[6];
      #pragma unroll
      for (int nt = 0; nt < 6; nt++) acc2[nt] = f32x4{0.f, 0.f, 0.f, 0.f};
      #pragma unroll
      for (int ks = 0; ks < 4; ks++) {
        #pragma unroll
        for (int nt = 0; nt < 6; nt++) {
          f16x8 b = *(const f16x8*)(W2 + (ks * 6 + nt) * 512 + lane * 8);
          acc2[nt] = __builtin_amdgcn_mfma_f32_16x16x32_f16(a2.v[ks], b, acc2[nt], 0, 0, 0);
        }
      }
      // fold layer 3: coef[m] = sum_c celu(z2[m][c]) * w3[c]
      float pr[4] = {0.f, 0.f, 0.f, 0.f};
      #pragma unroll
      for (int nt = 0; nt < 6; nt++) {
        #pragma unroll
        for (int r = 0; r < 4; r++) {
          float v = celu01(acc2[nt][r] + b2v[nt]);
          pr[r] += v * w3v[nt];
        }
      }
      #pragma unroll
      for (int m = 1; m < 16; m <<= 1) {
        #pragma unroll
        for (int r = 0; r < 4; r++) pr[r] += __shfl_xor(pr[r], m);
      }
      if (nlo == 0) {
        #pragma unroll
        for (int r = 0; r < 4; r++) {
          int row = (t0 + i) * 16 + q * 4 + r;
          if (row < cnt)
            p.out[atoms_l[i * 16 + q * 4 + r]] = b0v + b1v * (pr[r] + b3);
        }
      }
    }
    asm volatile("s_waitcnt lgkmcnt(0)" ::: "memory");
    __builtin_amdgcn_s_barrier();        // ldsA free for next batch's phase A
  }
}

// LDS 130.6KB -> 1 block/CU; (640,2) -> VGPR cap 256 (R10: 84 live, +ldC ~96)
__global__ __launch_bounds__(640, 2) void fused_kernel(GemmParams p) {
  __shared__ __align__(16) char smem[133760];
  int s = blockIdx.x & 3, bl = blockIdx.x >> 2;
  switch (s) {
    case 0: fused_body<10, 5>(p, 0, bl, smem); break;  // H: 384->160->128->96->1
    case 1: fused_body<10, 5>(p, 1, bl, smem); break;  // C: 384->144->112->96->1
    case 2: fused_body<8, 4>(p, 2, bl, smem); break;   // N: 384->128->112->96->1
    default: fused_body<8, 4>(p, 3, bl, smem); break;  // O
  }
}

// ============================================================================

extern "C" void kernel_launch(void* const* d_in, const int* in_sizes, int n_in,
                              void* d_out, int out_size, void* d_ws, size_t ws_size,
                              hipStream_t stream) {
  if (ws_size < WS_NEEDED) return;  // workspace too small — fail loud

  const int* species = (const int*)d_in[0];
  const float* aev = (const float*)d_in[1];
  const float* b0 = (const float*)d_in[2];
  const float* b1 = (const float*)d_in[3];

  static const int F1[4]  = {160, 144, 128, 128};
  static const int F1p[4] = {160, 160, 128, 128};
  static const int F2[4]  = {128, 112, 112, 112};

  char* wsb = (char*)d_ws;
  int* counts = (int*)wsb;
  u16* lists = (u16*)(wsb + WS_LISTS_OFF);
  f16* wbase = (f16*)(wsb + WS_W_OFF);

  PrepParams pp;
  pp.species = species; pp.counts = counts; pp.lists = lists; pp.wbase = wbase;

  GemmParams mp;
  mp.aev = aev; mp.b0 = b0; mp.b1 = b1;
  mp.counts = counts; mp.lists = lists; mp.out = (float*)d_out;

  int off = 0, ji = 0;
  for (int s = 0; s < 4; s++) {
    int K[4]  = {384, F1[s], F2[s], 96};
    int N[4]  = {F1[s], F2[s], 96, 1};
    int KS[4] = {12, F1p[s] / 32, 4, 3};
    int NT[4] = {F1p[s] / 16, 8, 6, 1};
    int CK[4] = {1, 1, 1, 3};
    for (int l = 0; l < 4; l++) {
      const float* w = (const float*)d_in[4 + s * 8 + l * 2];
      const float* b = (const float*)d_in[4 + s * 8 + l * 2 + 1];
      pp.jobs[ji].src = w;
      pp.jobs[ji].K = K[l];
      pp.jobs[ji].N = N[l];
      pp.jobs[ji].KS = KS[l];
      pp.jobs[ji].NT = NT[l];
      pp.jobs[ji].CK = CK[l];
      pp.jobs[ji].off = off;
      mp.w[s][l] = wbase + off;
      mp.bias[s][l] = b;
      off += KS[l] * NT[l] * 512;
      ji++;
    }
    mp.w3src[s] = (const float*)d_in[4 + s * 8 + 6];
    mp.Nreal0[s] = F1[s];
    mp.Nreal1[s] = F2[s];
  }

  hipMemsetAsync(d_ws, 0, 64, stream);
  prep_kernel<<<dim3(256 + 480), 256, 0, stream>>>(pp);
  fused_kernel<<<dim3(4 * BLKF), 640, 0, stream>>>(mp);
}

// Round 14
// 243.720 us; speedup vs baseline: 1.0858x; 1.0858x over previous
//
#include <hip/hip_runtime.h>

typedef _Float16 f16;
typedef _Float16 f16x4 __attribute__((ext_vector_type(4)));
typedef _Float16 f16x8 __attribute__((ext_vector_type(8)));
typedef float f32x4 __attribute__((ext_vector_type(4)));
typedef unsigned short u16;
typedef unsigned int u32;

#define NATOMS 65536
#define CAP 17920            // per-species atom capacity (~+13 sigma vs expected 16384)

// ---------------- workspace layout (lists + packed weights only) ---------------
#define WS_LISTS_OFF 256
#define WS_W_OFF 524544
#define WS_W_ELEMS 350208
#define WS_NEEDED (WS_W_OFF + WS_W_ELEMS * 2)

#define BLKF 64   // fused: blocks per species -> grid 256 (640 thr, 1 block/CU)

// aev staging geometry: 16-atom tile
#define ROWB 1536            // bytes per aev row (384 f32)
#define ROWH 768             // bytes per LDS row (384 f16)
#define TILEH 12288          // 16 x 768 B f16 tile

struct ConvJob { const float* src; int K, N, KS, NT, CK, off; };

struct PrepParams {
  const int* species;
  int* counts;
  u16* lists;
  f16* wbase;
  ConvJob jobs[16];
};

struct GemmParams {
  const float* aev;
  const float* b0;
  const float* b1;
  const float* bias[4][4];
  const float* w3src[4];    // original fp32 layer-3 weights [96][1]
  const f16* w[4][4];       // fragment-packed, chunk-major (frag = ks*NT + nt)
  const int* counts;
  const u16* lists;
  float* out;
  int Nreal0[4];            // {160,144,128,128}
  int Nreal1[4];            // {128,112,112,112}
};

// A-fragment bundle passed BY VALUE so SROA keeps it in VGPRs.
template <int N> struct AF { f16x8 v[N]; };

// ---------------- prep: routing (blocks 0..255) + weight pack (blocks 256..735) ----
__global__ __launch_bounds__(256) void prep_kernel(PrepParams p) {
  int tid = threadIdx.x;
  if (blockIdx.x < 256) {
    __shared__ int wcnt[4][4];
    __shared__ int wbase[4][4];
    int i = blockIdx.x * 256 + tid;
    int s = p.species[i];
    int wave = tid >> 6, lane = tid & 63;
    unsigned long long m[4];
    #pragma unroll
    for (int t = 0; t < 4; t++) {
      m[t] = __ballot(s == t);
      if (lane == 0) wcnt[wave][t] = __popcll(m[t]);
    }
    __syncthreads();
    if (tid < 4) {
      int t = tid;
      int c0 = wcnt[0][t], c1 = wcnt[1][t], c2 = wcnt[2][t], c3 = wcnt[3][t];
      int base = atomicAdd(&p.counts[t], c0 + c1 + c2 + c3);
      wbase[0][t] = base;
      wbase[1][t] = base + c0;
      wbase[2][t] = base + c0 + c1;
      wbase[3][t] = base + c0 + c1 + c2;
    }
    __syncthreads();
    int rnk = __popcll(m[s] & ((1ull << lane) - 1ull));
    p.lists[s * NATOMS + wbase[wave][s] + rnk] = (u16)i;
  } else {
    // pack fp32 [K][N] -> fp16 fragments, chunk-major consumption order
    int bx = blockIdx.x - 256;
    int job = bx / 30, bxin = bx - job * 30;
    ConvJob jb = p.jobs[job];
    int e = bxin * 256 + tid;
    int nslots = jb.KS * jb.NT * 64;
    if (e >= nslots) return;
    int frag = e >> 6, lane = e & 63;
    int c = frag / (jb.CK * jb.NT);
    int rem = frag - c * (jb.CK * jb.NT);
    int ckc = min(jb.CK, jb.KS - c * jb.CK);
    int nt = rem / ckc, ki = rem - nt * ckc;
    int ks = c * jb.CK + ki;
    int q = lane >> 4, nlo = lane & 15;
    int n = nt * 16 + nlo;
    int k0 = ks * 32 + q * 8;
    f16x8 v;
    #pragma unroll
    for (int j = 0; j < 8; j++) {
      int k = k0 + j;
      float x = (n < jb.N && k < jb.K) ? jb.src[k * jb.N + n] : 0.f;
      v[j] = (f16)x;
    }
    *(f16x8*)(p.wbase + jb.off + (size_t)e * 8) = v;
  }
}

__device__ __forceinline__ float celu01(float v) {
  return v > 0.f ? v : 0.1f * (__expf(v * 10.f) - 1.f);
}

// stage one 1KB fragment (64 lanes x 16B) global -> LDS (weight staging)
__device__ __forceinline__ void stage_frag(const f16* g, f16* l, int lane) {
  __builtin_amdgcn_global_load_lds(
      (const __attribute__((address_space(1))) u32*)(g + lane * 8),
      (__attribute__((address_space(3))) u32*)l, 16, 0, 0);
}

// ============================================================================
// fused : aev(f32)[gathered] -> L0 -> celu -> (z0 in LDS) -> L1 -> celu
//         -> (in-place transpose) -> L2 -> celu -> dot w3 -> shifter -> out.
//
// R14 = EXACT R10 (verified best: fused 63.5us, VGPR 84, bench 246.9) + ONE
// additive technique: T5 s_setprio(1) around the MFMA clusters.  Phase A has
// the wave role-split T5 requires (stagers issuing VMEM vs compute waves in
// MFMA) -- the m191 attn regime, not m190's lockstep null.  Depth/cadence
// experiments are DEAD: R12 (2x work/period) = +19%, R13 (depth-3) = +43%;
// every pipeline deepening regressed, so R10's phase A is the structural
// local optimum and only issue-arbitration remains addressable at source.
// ============================================================================
template <int NT0, int KS1>   // H/C: <10,5>  N/O: <8,4>
__device__ void fused_body(const GemmParams& p, int s, int bl, char* smem) {
  constexpr int LDSA_OFF = 2 * TILEH;                  // 24576
  constexpr int TSTRIDE = 16 * 168;                    // f16 per ldsA tile
  constexpr int W1_OFF = LDSA_OFF + 8 * TSTRIDE * 2;   // 67584
  constexpr int W2_OFF = W1_OFF + 40 * 512 * 2;        // 108544
  constexpr int ATOMS_OFF = W2_OFF + 24 * 512 * 2;     // 133120
  constexpr int NF1 = KS1 * 8;

  int tid = threadIdx.x, w = tid >> 6, lane = tid & 63;
  int q = lane >> 4, nlo = lane & 15;
  int cnt = min(p.counts[s], CAP);
  int ntiles = (cnt + 15) >> 4;
  int tpb = (ntiles + BLKF - 1) / BLKF;
  int t0 = bl * tpb;
  int nt_blk = min(ntiles - t0, tpb);
  if (nt_blk <= 0) return;               // uniform block-wide exit (before barriers)

  f16* ldsA = (f16*)(smem + LDSA_OFF);
  f16* W1 = (f16*)(smem + W1_OFF);
  f16* W2 = (f16*)(smem + W2_OFF);
  u16* atoms_l = (u16*)(smem + ATOMS_OFF);

  // W1/W2 -> LDS once per block (wave-uniform loop)
  const f16* g1 = p.w[s][1];
  const f16* g2 = p.w[s][2];
  for (int f = w; f < NF1 + 24; f += 10) {
    if (f < NF1) stage_frag(g1 + (size_t)f * 512, W1 + f * 512, lane);
    else stage_frag(g2 + (size_t)(f - NF1) * 512, W2 + (f - NF1) * 512, lane);
  }

  // W0 fragments (A-operand: row=n) + phase-A bias, VGPR-resident
  f16x8 wf[12];
  float bvv[4];
  if (w < NT0) {
    const f16* wg = p.w[s][0];
    #pragma unroll
    for (int ks = 0; ks < 12; ks++)
      wf[ks] = *(const f16x8*)(wg + (size_t)(ks * NT0 + w) * 512 + lane * 8);
    #pragma unroll
    for (int r = 0; r < 4; r++) {
      int n = w * 16 + q * 4 + r;
      bvv[r] = (n < p.Nreal0[s]) ? p.bias[s][0][n] : 0.f;
    }
  }

  // phase-B constants (persist across batches)
  int Nr1 = p.Nreal1[s];
  const float* bias1 = p.bias[s][1];
  const float* bias2 = p.bias[s][2];
  const float* w3 = p.w3src[s];
  float bv1[8], b2v[6], w3v[6];
  #pragma unroll
  for (int nt = 0; nt < 8; nt++) {
    int n = nt * 16 + nlo;
    bv1[nt] = (n < Nr1) ? bias1[n] : 0.f;
  }
  #pragma unroll
  for (int nt = 0; nt < 6; nt++) {
    int n = nt * 16 + nlo;    // 0..95, all real
    b2v[nt] = bias2[n];
    w3v[nt] = w3[n];
  }
  float b3 = p.bias[s][3][0];
  float b0v = p.b0[s], b1v = p.b1[s];

  // atom ids -> LDS (subsequent reads are lgkm ops; tpb<=18 -> <=288 entries)
  const u16* list = p.lists + s * NATOMS;
  for (int idx = tid; idx < nt_blk * 16; idx += 640)
    atoms_l[idx] = list[min(t0 * 16 + idx, cnt - 1)];
  __syncthreads();   // drains W1/W2 DMAs + wf/bias/atom loads; pipeline empty

  bool stager = (w < 8);
  int frow[3], fintra[3];
  #pragma unroll
  for (int j = 0; j < 3; j++) {
    int o32 = (w + 8 * j) * 1024 + lane * 16;
    frow[j] = o32 / ROWB;
    fintra[j] = o32 - frow[j] * ROWB;
  }

  f32x4 ld[3];   // in-flight tile (static-indexed -> stays in VGPRs)
  auto issue = [&](int i) {              // global gather, tile i -> ld[]
    #pragma unroll
    for (int j = 0; j < 3; j++) {
      int atom = atoms_l[i * 16 + frow[j]];
      ld[j] = *(const f32x4*)((const char*)p.aev + (size_t)atom * ROWB + fintra[j]);
    }
  };
  auto write_lds = [&](int i) {          // ld[] -> f16 -> ring slot i&1, swizzled
    char* buf = smem + (i & 1) * TILEH;
    #pragma unroll
    for (int j = 0; j < 3; j++) {
      int o16 = (w + 8 * j) * 512 + lane * 8;
      int addr = o16 ^ ((frow[j] & 7) << 4);
      f16x4 h = {(f16)ld[j][0], (f16)ld[j][1], (f16)ld[j][2], (f16)ld[j][3]};
      *(f16x4*)(buf + addr) = h;
    }
  };

  for (int lo = 0; lo < nt_blk; lo += 8) {
    int hi = min(nt_blk, lo + 8);

    // ---- phase A: pipelined z0 for tiles [lo,hi) -> ldsA ----
    if (stager) {
      issue(lo);
      write_lds(lo);                     // compiler waits exactly on ld[] here
      if (lo + 1 < hi) issue(lo + 1);
    }
    asm volatile("s_waitcnt lgkmcnt(0)" ::: "memory");
    __builtin_amdgcn_s_barrier();

    for (int i = lo; i < hi; i++) {
      if (stager) {
        if (i + 1 < hi) write_lds(i + 1);   // slot (i+1)&1 free since barrier i-1
        if (i + 2 < hi) issue(i + 2);       // overlaps compute below
      }
      if (w < NT0) {
        const char* buf = smem + (i & 1) * TILEH;
        int swz = (nlo & 7) << 4;
        int base = nlo * ROWH + q * 16;
        f32x4 acc = {0.f, 0.f, 0.f, 0.f};
        __builtin_amdgcn_s_setprio(1);   // T5: MFMA waves win issue arbitration
        #pragma unroll
        for (int ks = 0; ks < 12; ks++) {
          f16x8 a = *(const f16x8*)(buf + ((base + ks * 64) ^ swz));
          acc = __builtin_amdgcn_mfma_f32_16x16x32_f16(wf[ks], a, acc, 0, 0, 0);
        }
        __builtin_amdgcn_s_setprio(0);
        // z0-celu -> ldsA[i-lo], row=atom(nlo), cols w*16+q*4..+4 (one b64 store)
        f16* A = ldsA + (i - lo) * TSTRIDE;
        f16x4 o;
        #pragma unroll
        for (int r = 0; r < 4; r++) o[r] = (f16)celu01(acc[r] + bvv[r]);
        *(f16x4*)(A + nlo * 168 + w * 16 + q * 4) = o;
      }
      asm volatile("s_waitcnt lgkmcnt(0)" ::: "memory");
      __builtin_amdgcn_s_barrier();      // ring slot reuse + ldsA tile visible
    }

    // ---- phase B: wave w consumes ldsA[w] (tile lo+w); W1/W2 from LDS ----
    if (w < 8 && lo + w < hi) {
      int i = lo + w;
      f16* A = ldsA + w * TSTRIDE;
      AF<KS1> a1;
      #pragma unroll
      for (int ks = 0; ks < KS1; ks++)
        a1.v[ks] = *(const f16x8*)(A + nlo * 168 + ks * 32 + q * 8);
      f32x4 acc1[8];
      #pragma unroll
      for (int nt = 0; nt < 8; nt++) acc1[nt] = f32x4{0.f, 0.f, 0.f, 0.f};
      __builtin_amdgcn_s_setprio(1);
      #pragma unroll
      for (int ks = 0; ks < KS1; ks++) {
        #pragma unroll
        for (int nt = 0; nt < 8; nt++) {
          f16x8 b = *(const f16x8*)(W1 + (ks * 8 + nt) * 512 + lane * 8);
          acc1[nt] = __builtin_amdgcn_mfma_f32_16x16x32_f16(a1.v[ks], b, acc1[nt], 0, 0, 0);
        }
      }
      __builtin_amdgcn_s_setprio(0);
      // z1-celu transpose into the SAME tile region (a1 already in regs;
      // every write depends on all a1 reads through acc1 -> no hazard)
      #pragma unroll
      for (int nt = 0; nt < 8; nt++) {
        #pragma unroll
        for (int r = 0; r < 4; r++)
          A[(q * 4 + r) * 168 + nt * 16 + nlo] = (f16)celu01(acc1[nt][r] + bv1[nt]);
      }
      AF<4> a2;
      #pragma unroll
      for (int ks = 0; ks < 4; ks++)
        a2.v[ks] = *(const f16x8*)(A + nlo * 168 + ks * 32 + q * 8);
      f32x4 acc2[6];
      #pragma unroll
      for (int nt = 0; nt < 6; nt++) acc2[nt] = f32x4{0.f, 0.f, 0.f, 0.f};
      __builtin_amdgcn_s_setprio(1);
      #pragma unroll
      for (int ks = 0; ks < 4; ks++) {
        #pragma unroll
        for (int nt = 0; nt < 6; nt++) {
          f16x8 b = *(const f16x8*)(W2 + (ks * 6 + nt) * 512 + lane * 8);
          acc2[nt] = __builtin_amdgcn_mfma_f32_16x16x32_f16(a2.v[ks], b, acc2[nt], 0, 0, 0);
        }
      }
      __builtin_amdgcn_s_setprio(0);
      // fold layer 3: coef[m] = sum_c celu(z2[m][c]) * w3[c]
      float pr[4] = {0.f, 0.f, 0.f, 0.f};
      #pragma unroll
      for (int nt = 0; nt < 6; nt++) {
        #pragma unroll
        for (int r = 0; r < 4; r++) {
          float v = celu01(acc2[nt][r] + b2v[nt]);
          pr[r] += v * w3v[nt];
        }
      }
      #pragma unroll
      for (int m = 1; m < 16; m <<= 1) {
        #pragma unroll
        for (int r = 0; r < 4; r++) pr[r] += __shfl_xor(pr[r], m);
      }
      if (nlo == 0) {
        #pragma unroll
        for (int r = 0; r < 4; r++) {
          int row = (t0 + i) * 16 + q * 4 + r;
          if (row < cnt)
            p.out[atoms_l[i * 16 + q * 4 + r]] = b0v + b1v * (pr[r] + b3);
        }
      }
    }
    asm volatile("s_waitcnt lgkmcnt(0)" ::: "memory");
    __builtin_amdgcn_s_barrier();        // ldsA free for next batch's phase A
  }
}

// LDS 130.6KB -> 1 block/CU; (640,2) -> VGPR cap 256 (84 live, no spills)
__global__ __launch_bounds__(640, 2) void fused_kernel(GemmParams p) {
  __shared__ __align__(16) char smem[133760];
  int s = blockIdx.x & 3, bl = blockIdx.x >> 2;
  switch (s) {
    case 0: fused_body<10, 5>(p, 0, bl, smem); break;  // H: 384->160->128->96->1
    case 1: fused_body<10, 5>(p, 1, bl, smem); break;  // C: 384->144->112->96->1
    case 2: fused_body<8, 4>(p, 2, bl, smem); break;   // N: 384->128->112->96->1
    default: fused_body<8, 4>(p, 3, bl, smem); break;  // O
  }
}

// ============================================================================

extern "C" void kernel_launch(void* const* d_in, const int* in_sizes, int n_in,
                              void* d_out, int out_size, void* d_ws, size_t ws_size,
                              hipStream_t stream) {
  if (ws_size < WS_NEEDED) return;  // workspace too small — fail loud

  const int* species = (const int*)d_in[0];
  const float* aev = (const float*)d_in[1];
  const float* b0 = (const float*)d_in[2];
  const float* b1 = (const float*)d_in[3];

  static const int F1[4]  = {160, 144, 128, 128};
  static const int F1p[4] = {160, 160, 128, 128};
  static const int F2[4]  = {128, 112, 112, 112};

  char* wsb = (char*)d_ws;
  int* counts = (int*)wsb;
  u16* lists = (u16*)(wsb + WS_LISTS_OFF);
  f16* wbase = (f16*)(wsb + WS_W_OFF);

  PrepParams pp;
  pp.species = species; pp.counts = counts; pp.lists = lists; pp.wbase = wbase;

  GemmParams mp;
  mp.aev = aev; mp.b0 = b0; mp.b1 = b1;
  mp.counts = counts; mp.lists = lists; mp.out = (float*)d_out;

  int off = 0, ji = 0;
  for (int s = 0; s < 4; s++) {
    int K[4]  = {384, F1[s], F2[s], 96};
    int N[4]  = {F1[s], F2[s], 96, 1};
    int KS[4] = {12, F1p[s] / 32, 4, 3};
    int NT[4] = {F1p[s] / 16, 8, 6, 1};
    int CK[4] = {1, 1, 1, 3};
    for (int l = 0; l < 4; l++) {
      const float* w = (const float*)d_in[4 + s * 8 + l * 2];
      const float* b = (const float*)d_in[4 + s * 8 + l * 2 + 1];
      pp.jobs[ji].src = w;
      pp.jobs[ji].K = K[l];
      pp.jobs[ji].N = N[l];
      pp.jobs[ji].KS = KS[l];
      pp.jobs[ji].NT = NT[l];
      pp.jobs[ji].CK = CK[l];
      pp.jobs[ji].off = off;
      mp.w[s][l] = wbase + off;
      mp.bias[s][l] = b;
      off += KS[l] * NT[l] * 512;
      ji++;
    }
    mp.w3src[s] = (const float*)d_in[4 + s * 8 + 6];
    mp.Nreal0[s] = F1[s];
    mp.Nreal1[s] = F2[s];
  }

  hipMemsetAsync(d_ws, 0, 64, stream);
  prep_kernel<<<dim3(256 + 480), 256, 0, stream>>>(pp);
  fused_kernel<<<dim3(4 * BLKF), 640, 0, stream>>>(mp);
}